// Round 1
// baseline (2026.291 us; speedup 1.0000x reference)
//
#include <hip/hip_runtime.h>
#include <math.h>

#define N_NODES 100000
#define N_EDGES 800000
#define DIM_IN 128
#define DIM_OUT 256
#define NT 32  // nodes per block in the GEMM kernel

// -------- Kernel 1: scatter-add  m[dst] += x[src] --------------------------
// 32 threads per edge, each thread moves a float4 chunk (4 atomics).
__global__ __launch_bounds__(256) void gcn_scatter(
    const float* __restrict__ x,
    const int* __restrict__ src,
    const int* __restrict__ dst,
    float* __restrict__ m)
{
    int gid = blockIdx.x * 256 + threadIdx.x;
    int e = gid >> 5;          // edge id
    int c = gid & 31;          // float4 chunk within the 128-dim row
    if (e >= N_EDGES) return;
    int s = src[e];
    int d = dst[e];
    const float4 v = *reinterpret_cast<const float4*>(x + (size_t)s * DIM_IN + c * 4);
    float* mp = m + (size_t)d * DIM_IN + c * 4;
    atomicAdd(mp + 0, v.x);
    atomicAdd(mp + 1, v.y);
    atomicAdd(mp + 2, v.z);
    atomicAdd(mp + 3, v.w);
}

// -------- Kernel 2: h = gelu((m * deg_inv) @ W^T + b) ----------------------
// Block: 256 threads, handles NT=32 nodes x all 256 outputs.
// LDS: W transposed [128][256] (128 KB) + m tile [NT][128] (16 KB) = 144 KB.
__global__ __launch_bounds__(256) void gcn_gemm_gelu(
    const float* __restrict__ m,
    const float* __restrict__ deg_inv,
    const float* __restrict__ W,
    const float* __restrict__ b,
    float* __restrict__ out)
{
    extern __shared__ float lds[];
    float* Wt = lds;                        // [128][256] : Wt[k*256+o] = W[o*128+k]
    float* mt = lds + DIM_IN * DIM_OUT;     // [NT][128]

    const int tid = threadIdx.x;            // 0..255 == output column o
    // Load W transposed (conflict-free on read: lanes -> consecutive o).
    for (int i = tid; i < DIM_IN * DIM_OUT; i += 256) {
        int o = i >> 7;       // / DIM_IN
        int k = i & (DIM_IN - 1);
        Wt[k * DIM_OUT + o] = W[i];
    }
    const int node0 = blockIdx.x * NT;
    // Load m tile, pre-scaled by deg_inv.
    for (int i = tid; i < NT * DIM_IN; i += 256) {
        int n = i >> 7;
        int k = i & (DIM_IN - 1);
        int node = node0 + n;
        float v = 0.f;
        if (node < N_NODES) v = m[(size_t)node * DIM_IN + k] * deg_inv[node];
        mt[i] = v;
    }
    __syncthreads();

    float acc[NT];
#pragma unroll
    for (int n = 0; n < NT; ++n) acc[n] = 0.f;

    for (int k = 0; k < DIM_IN; k += 4) {
        float w0 = Wt[(k + 0) * DIM_OUT + tid];
        float w1 = Wt[(k + 1) * DIM_OUT + tid];
        float w2 = Wt[(k + 2) * DIM_OUT + tid];
        float w3 = Wt[(k + 3) * DIM_OUT + tid];
#pragma unroll
        for (int n = 0; n < NT; ++n) {
            float4 mv = *reinterpret_cast<const float4*>(&mt[n * DIM_IN + k]);
            acc[n] = fmaf(w0, mv.x, acc[n]);
            acc[n] = fmaf(w1, mv.y, acc[n]);
            acc[n] = fmaf(w2, mv.z, acc[n]);
            acc[n] = fmaf(w3, mv.w, acc[n]);
        }
    }

    const float bias = b[tid];
    for (int n = 0; n < NT; ++n) {
        int node = node0 + n;
        if (node < N_NODES) {
            float h = acc[n] + bias;
            float g = 0.5f * h * (1.0f + erff(h * 0.70710678118654752f));
            out[(size_t)node * DIM_OUT + tid] = g;
        }
    }
}

extern "C" void kernel_launch(void* const* d_in, const int* in_sizes, int n_in,
                              void* d_out, int out_size, void* d_ws, size_t ws_size,
                              hipStream_t stream) {
    const float* x       = (const float*)d_in[0];
    const int*   ei      = (const int*)d_in[1];      // [2][N_EDGES], int32
    const float* deg_inv = (const float*)d_in[2];
    const float* W       = (const float*)d_in[3];    // [256][128]
    const float* b       = (const float*)d_in[4];    // [256]
    float*       out     = (float*)d_out;

    const int* src = ei;             // row 0
    const int* dst = ei + N_EDGES;   // row 1

    float* m = (float*)d_ws;         // [N_NODES][DIM_IN] accumulator

    // Zero the accumulator every call (harness does not re-poison ws).
    hipMemsetAsync(m, 0, (size_t)N_NODES * DIM_IN * sizeof(float), stream);

    // Scatter: N_EDGES * 32 threads.
    {
        int total = N_EDGES * 32;
        int blocks = (total + 255) / 256;   // = 100000
        gcn_scatter<<<blocks, 256, 0, stream>>>(x, src, dst, m);
    }

    // GEMM + bias + GELU.
    {
        int blocks = (N_NODES + NT - 1) / NT;  // = 3125
        size_t lds_bytes = (size_t)(DIM_IN * DIM_OUT + NT * DIM_IN) * sizeof(float);
        gcn_gemm_gelu<<<blocks, 256, lds_bytes, stream>>>(m, deg_inv, W, b, out);
    }
}

// Round 2
// 477.783 us; speedup vs baseline: 4.2410x; 4.2410x over previous
//
#include <hip/hip_runtime.h>
#include <math.h>

#define N_NODES 100000
#define N_EDGES 800000
#define DIM_IN 128
#define DIM_OUT 256

constexpr int SCAN_B  = 1024;
constexpr int SCAN_NB = (N_NODES + SCAN_B - 1) / SCAN_B;   // 98

// ---------------- CSR build ------------------------------------------------
__global__ __launch_bounds__(256) void k_count(const int* __restrict__ dst,
                                               int* __restrict__ counts) {
    int e = blockIdx.x * 256 + threadIdx.x;   // grid sized exactly
    atomicAdd(&counts[dst[e]], 1);
}

__global__ __launch_bounds__(SCAN_B) void k_scan1(const int* __restrict__ counts,
                                                  int* __restrict__ incl,
                                                  int* __restrict__ bsum) {
    __shared__ int s[SCAN_B];
    int tid = threadIdx.x;
    int i = blockIdx.x * SCAN_B + tid;
    int v = (i < N_NODES) ? counts[i] : 0;
    s[tid] = v;
    __syncthreads();
    for (int off = 1; off < SCAN_B; off <<= 1) {
        int t = (tid >= off) ? s[tid - off] : 0;
        __syncthreads();
        s[tid] += t;
        __syncthreads();
    }
    if (i < N_NODES) incl[i] = s[tid];
    if (tid == SCAN_B - 1) bsum[blockIdx.x] = s[tid];
}

__global__ __launch_bounds__(128) void k_scan2(const int* __restrict__ bsum,
                                               int* __restrict__ boff) {
    __shared__ int s[128];
    int tid = threadIdx.x;
    int v = (tid < SCAN_NB) ? bsum[tid] : 0;
    s[tid] = v;
    __syncthreads();
    for (int off = 1; off < 128; off <<= 1) {
        int t = (tid >= off) ? s[tid - off] : 0;
        __syncthreads();
        s[tid] += t;
        __syncthreads();
    }
    if (tid < SCAN_NB) boff[tid] = s[tid];
}

__global__ __launch_bounds__(SCAN_B) void k_scan3(const int* __restrict__ counts,
                                                  int* __restrict__ incl,
                                                  const int* __restrict__ boff,
                                                  int* __restrict__ cursor) {
    int i = blockIdx.x * SCAN_B + threadIdx.x;
    if (i < N_NODES) {
        int base = (blockIdx.x > 0) ? boff[blockIdx.x - 1] : 0;
        int v = incl[i] + base;
        incl[i] = v;                 // global inclusive scan
        cursor[i] = v - counts[i];   // row start (exclusive)
    }
}

__global__ __launch_bounds__(256) void k_fill(const int* __restrict__ src,
                                              const int* __restrict__ dst,
                                              int* __restrict__ cursor,
                                              int* __restrict__ csr) {
    int e = blockIdx.x * 256 + threadIdx.x;
    int pos = atomicAdd(&cursor[dst[e]], 1);
    csr[pos] = src[e];
}

// ---------------- Aggregate: m[n] = deg_inv[n] * sum_{e in CSR(n)} x[src] --
// One wave per node; lane holds float2 of the 128-dim row.
__global__ __launch_bounds__(256) void k_agg(const float* __restrict__ x,
                                             const int* __restrict__ csr,
                                             const int* __restrict__ incl,
                                             const int* __restrict__ counts,
                                             const float* __restrict__ deg_inv,
                                             float* __restrict__ m) {
    int wave = threadIdx.x >> 6;
    int lane = threadIdx.x & 63;
    int node = blockIdx.x * 4 + wave;
    if (node >= N_NODES) return;
    int end = __builtin_amdgcn_readfirstlane(incl[node]);
    int beg = end - __builtin_amdgcn_readfirstlane(counts[node]);
    float a0 = 0.f, a1 = 0.f;
    for (int e = beg; e < end; ++e) {
        int s = csr[e];  // wave-uniform -> scalar load
        const float2 v = *reinterpret_cast<const float2*>(x + (size_t)s * DIM_IN + lane * 2);
        a0 += v.x;
        a1 += v.y;
    }
    float d = deg_inv[node];
    float2 r; r.x = a0 * d; r.y = a1 * d;
    *reinterpret_cast<float2*>(m + (size_t)node * DIM_IN + lane * 2) = r;
}

// ---------------- Fallback aggregate (atomics) if ws too small -------------
__global__ __launch_bounds__(256) void gcn_scatter(const float* __restrict__ x,
                                                   const int* __restrict__ src,
                                                   const int* __restrict__ dst,
                                                   float* __restrict__ m) {
    int gid = blockIdx.x * 256 + threadIdx.x;
    int e = gid >> 5;
    int c = gid & 31;
    if (e >= N_EDGES) return;
    int s = src[e];
    int d = dst[e];
    const float4 v = *reinterpret_cast<const float4*>(x + (size_t)s * DIM_IN + c * 4);
    float* mp = m + (size_t)d * DIM_IN + c * 4;
    atomicAdd(mp + 0, v.x);
    atomicAdd(mp + 1, v.y);
    atomicAdd(mp + 2, v.z);
    atomicAdd(mp + 3, v.w);
}

__global__ __launch_bounds__(256) void k_scale(float* __restrict__ m,
                                               const float* __restrict__ deg_inv) {
    int i = blockIdx.x * 256 + threadIdx.x;  // one thread per element
    if (i < N_NODES * DIM_IN) {
        m[i] *= deg_inv[i >> 7];
    }
}

// ---------------- GEMM + bias + exact GELU ---------------------------------
// Block 256 = 4 waves. lane = node within 64-node tile; wave w owns outputs
// [w*64, w*64+64). W/b read via wave-uniform addresses -> s_load (SGPR
// operands), m rows read per-lane as float4 (L1-line reuse across k).
__global__ __launch_bounds__(256) void k_gemm(const float* __restrict__ m,
                                              const float* __restrict__ W,
                                              const float* __restrict__ b,
                                              float* __restrict__ out) {
    int wave = threadIdx.x >> 6;
    int lane = threadIdx.x & 63;
    int node = blockIdx.x * 64 + lane;
    int nclamp = node < N_NODES ? node : N_NODES - 1;
    int o0 = __builtin_amdgcn_readfirstlane(wave * 64);

    float acc[64];
#pragma unroll
    for (int o = 0; o < 64; ++o) acc[o] = 0.f;

    const float* mrow = m + (size_t)nclamp * DIM_IN;
    for (int k4 = 0; k4 < DIM_IN / 4; ++k4) {
        const float4 mv = *reinterpret_cast<const float4*>(mrow + k4 * 4);
#pragma unroll
        for (int o = 0; o < 64; ++o) {
            const float4 w = *reinterpret_cast<const float4*>(W + (size_t)(o0 + o) * DIM_IN + k4 * 4);
            acc[o] = fmaf(mv.x, w.x, acc[o]);
            acc[o] = fmaf(mv.y, w.y, acc[o]);
            acc[o] = fmaf(mv.z, w.z, acc[o]);
            acc[o] = fmaf(mv.w, w.w, acc[o]);
        }
    }

    if (node < N_NODES) {
        float* orow = out + (size_t)node * DIM_OUT + o0;
#pragma unroll
        for (int og = 0; og < 16; ++og) {
            float4 r;
            float h0 = acc[og * 4 + 0] + b[o0 + og * 4 + 0];
            float h1 = acc[og * 4 + 1] + b[o0 + og * 4 + 1];
            float h2 = acc[og * 4 + 2] + b[o0 + og * 4 + 2];
            float h3 = acc[og * 4 + 3] + b[o0 + og * 4 + 3];
            r.x = 0.5f * h0 * (1.0f + erff(h0 * 0.70710678118654752f));
            r.y = 0.5f * h1 * (1.0f + erff(h1 * 0.70710678118654752f));
            r.z = 0.5f * h2 * (1.0f + erff(h2 * 0.70710678118654752f));
            r.w = 0.5f * h3 * (1.0f + erff(h3 * 0.70710678118654752f));
            *reinterpret_cast<float4*>(orow + og * 4) = r;
        }
    }
}

extern "C" void kernel_launch(void* const* d_in, const int* in_sizes, int n_in,
                              void* d_out, int out_size, void* d_ws, size_t ws_size,
                              hipStream_t stream) {
    const float* x       = (const float*)d_in[0];
    const int*   ei      = (const int*)d_in[1];
    const float* deg_inv = (const float*)d_in[2];
    const float* W       = (const float*)d_in[3];
    const float* bias    = (const float*)d_in[4];
    float*       out     = (float*)d_out;

    const int* src = ei;
    const int* dst = ei + N_EDGES;

    // ws layout: m first, then CSR ints.
    float* m = (float*)d_ws;
    size_t m_bytes = (size_t)N_NODES * DIM_IN * sizeof(float);          // 51.2 MB
    int* counts = (int*)((char*)d_ws + m_bytes);
    int* incl   = counts + N_NODES;
    int* cursor = incl + N_NODES;
    int* bsum   = cursor + N_NODES;
    int* boff   = bsum + 128;
    int* csr    = boff + 128;
    size_t need = m_bytes + sizeof(int) * ((size_t)3 * N_NODES + 256 + N_EDGES);

    if (ws_size >= need) {
        // ---- fast path: CSR build + gather aggregate ----
        hipMemsetAsync(counts, 0, N_NODES * sizeof(int), stream);
        k_count<<<N_EDGES / 256, 256, 0, stream>>>(dst, counts);
        k_scan1<<<SCAN_NB, SCAN_B, 0, stream>>>(counts, incl, bsum);
        k_scan2<<<1, 128, 0, stream>>>(bsum, boff);
        k_scan3<<<SCAN_NB, SCAN_B, 0, stream>>>(counts, incl, boff, cursor);
        k_fill<<<N_EDGES / 256, 256, 0, stream>>>(src, dst, cursor, csr);
        k_agg<<<(N_NODES + 3) / 4, 256, 0, stream>>>(x, csr, incl, counts, deg_inv, m);
    } else {
        // ---- fallback: atomic scatter (known to fit 51.2 MB) ----
        hipMemsetAsync(m, 0, m_bytes, stream);
        {
            int total = N_EDGES * 32;
            gcn_scatter<<<(total + 255) / 256, 256, 0, stream>>>(x, src, dst, m);
        }
        k_scale<<<(N_NODES * DIM_IN + 255) / 256, 256, 0, stream>>>(m, deg_inv);
    }

    k_gemm<<<(N_NODES + 63) / 64, 256, 0, stream>>>(m, W, bias, out);
}

// Round 3
// 242.778 us; speedup vs baseline: 8.3463x; 1.9680x over previous
//
#include <hip/hip_runtime.h>
#include <math.h>

#define N_NODES 100000
#define N_EDGES 800000
#define DIM_IN 128
#define DIM_OUT 256

constexpr int SCAN_B  = 1024;
constexpr int SCAN_NB = (N_NODES + SCAN_B - 1) / SCAN_B;   // 98

typedef __bf16 bf16x8 __attribute__((ext_vector_type(8)));
typedef float  f32x4  __attribute__((ext_vector_type(4)));

// ---------------- CSR build ------------------------------------------------
__global__ __launch_bounds__(256) void k_count(const int* __restrict__ dst,
                                               int* __restrict__ counts) {
    int e = blockIdx.x * 256 + threadIdx.x;   // grid sized exactly (800000/256)
    atomicAdd(&counts[dst[e]], 1);
}

__global__ __launch_bounds__(SCAN_B) void k_scan1(const int* __restrict__ counts,
                                                  int* __restrict__ incl,
                                                  int* __restrict__ bsum) {
    __shared__ int s[SCAN_B];
    int tid = threadIdx.x;
    int i = blockIdx.x * SCAN_B + tid;
    int v = (i < N_NODES) ? counts[i] : 0;
    s[tid] = v;
    __syncthreads();
    for (int off = 1; off < SCAN_B; off <<= 1) {
        int t = (tid >= off) ? s[tid - off] : 0;
        __syncthreads();
        s[tid] += t;
        __syncthreads();
    }
    if (i < N_NODES) incl[i] = s[tid];
    if (tid == SCAN_B - 1) bsum[blockIdx.x] = s[tid];
}

__global__ __launch_bounds__(128) void k_scan2(const int* __restrict__ bsum,
                                               int* __restrict__ boff) {
    __shared__ int s[128];
    int tid = threadIdx.x;
    int v = (tid < SCAN_NB) ? bsum[tid] : 0;
    s[tid] = v;
    __syncthreads();
    for (int off = 1; off < 128; off <<= 1) {
        int t = (tid >= off) ? s[tid - off] : 0;
        __syncthreads();
        s[tid] += t;
        __syncthreads();
    }
    if (tid < SCAN_NB) boff[tid] = s[tid];
}

__global__ __launch_bounds__(SCAN_B) void k_scan3(const int* __restrict__ counts,
                                                  int* __restrict__ incl,
                                                  const int* __restrict__ boff,
                                                  int* __restrict__ cursor) {
    int i = blockIdx.x * SCAN_B + threadIdx.x;
    if (i < N_NODES) {
        int base = (blockIdx.x > 0) ? boff[blockIdx.x - 1] : 0;
        int v = incl[i] + base;
        incl[i] = v;                 // global inclusive scan
        cursor[i] = v - counts[i];   // row start (exclusive)
    }
}

__global__ __launch_bounds__(256) void k_fill(const int* __restrict__ src,
                                              const int* __restrict__ dst,
                                              int* __restrict__ cursor,
                                              int* __restrict__ csr) {
    int e = blockIdx.x * 256 + threadIdx.x;
    int pos = atomicAdd(&cursor[dst[e]], 1);
    csr[pos] = src[e];
}

// ---------------- Aggregate: mb[n] = bf16( deg_inv[n] * sum x[src] ) -------
// One wave per node; lane holds float2 of the 128-dim row; packed bf16 store.
__global__ __launch_bounds__(256) void k_agg(const float* __restrict__ x,
                                             const int* __restrict__ csr,
                                             const int* __restrict__ incl,
                                             const int* __restrict__ counts,
                                             const float* __restrict__ deg_inv,
                                             unsigned short* __restrict__ mb) {
    int wave = threadIdx.x >> 6;
    int lane = threadIdx.x & 63;
    int node = blockIdx.x * 4 + wave;
    if (node >= N_NODES) return;
    int end = __builtin_amdgcn_readfirstlane(incl[node]);
    int beg = end - __builtin_amdgcn_readfirstlane(counts[node]);
    float a0 = 0.f, a1 = 0.f;
    for (int e = beg; e < end; ++e) {
        int s = csr[e];  // wave-uniform -> scalar load
        const float2 v = *reinterpret_cast<const float2*>(x + (size_t)s * DIM_IN + lane * 2);
        a0 += v.x;
        a1 += v.y;
    }
    float d = deg_inv[node];
    unsigned short u0 = __builtin_bit_cast(unsigned short, (__bf16)(a0 * d));
    unsigned short u1 = __builtin_bit_cast(unsigned short, (__bf16)(a1 * d));
    reinterpret_cast<unsigned int*>(mb + (size_t)node * DIM_IN)[lane] =
        (unsigned int)u0 | ((unsigned int)u1 << 16);
}

// ---------------- W f32 -> bf16 --------------------------------------------
__global__ __launch_bounds__(256) void k_cvtW(const float* __restrict__ W,
                                              unsigned short* __restrict__ Wb) {
    int i = blockIdx.x * 256 + threadIdx.x;   // 32768 total, grid exact
    Wb[i] = __builtin_bit_cast(unsigned short, (__bf16)W[i]);
}

// ---------------- MFMA GEMM + bias + exact GELU ----------------------------
// Block: 256 thr = 4 waves, 64 nodes x 256 outs. Wave w: 64x64 tile = 4x4
// frags of mfma_f32_16x16x32_bf16, K=128 in 4 steps. A = mb rows (node,k),
// B = Wb rows (out,k) -- both 8 contiguous bf16 per lane, direct global loads.
__global__ __launch_bounds__(256) void k_mfma_gemm(
    const unsigned short* __restrict__ mb,
    const unsigned short* __restrict__ Wb,
    const float* __restrict__ bias,
    float* __restrict__ out)
{
    const int wave = threadIdx.x >> 6;
    const int lane = threadIdx.x & 63;
    const int n0 = blockIdx.x * 64;
    const int o0 = wave * 64;
    const int lr = lane & 15;     // A-row / B-col / D-col
    const int kg = lane >> 4;     // k-group (8 contiguous k each)

    f32x4 acc[4][4] = {};

#pragma unroll
    for (int ks = 0; ks < 4; ++ks) {
        const int koff = ks * 32 + kg * 8;
        bf16x8 afr[4], bfr[4];
#pragma unroll
        for (int mt = 0; mt < 4; ++mt) {
            int node = n0 + mt * 16 + lr;
            node = node < N_NODES ? node : N_NODES - 1;
            afr[mt] = *reinterpret_cast<const bf16x8*>(mb + (size_t)node * DIM_IN + koff);
        }
#pragma unroll
        for (int nt = 0; nt < 4; ++nt) {
            int o = o0 + nt * 16 + lr;
            bfr[nt] = *reinterpret_cast<const bf16x8*>(Wb + (size_t)o * DIM_IN + koff);
        }
#pragma unroll
        for (int mt = 0; mt < 4; ++mt)
#pragma unroll
            for (int nt = 0; nt < 4; ++nt)
                acc[mt][nt] = __builtin_amdgcn_mfma_f32_16x16x32_bf16(
                    afr[mt], bfr[nt], acc[mt][nt], 0, 0, 0);
    }

    // Epilogue. D mapping: col = lane&15, row = (lane>>4)*4 + reg.
    const int rb = kg * 4;
#pragma unroll
    for (int nt = 0; nt < 4; ++nt) {
        const float bval = bias[o0 + nt * 16 + lr];
#pragma unroll
        for (int mt = 0; mt < 4; ++mt) {
#pragma unroll
            for (int r = 0; r < 4; ++r) {
                int node = n0 + mt * 16 + rb + r;
                if (node < N_NODES) {
                    float h = acc[mt][nt][r] + bval;
                    float g = 0.5f * h * (1.0f + erff(h * 0.70710678118654752f));
                    out[(size_t)node * DIM_OUT + o0 + nt * 16 + lr] = g;
                }
            }
        }
    }
}

extern "C" void kernel_launch(void* const* d_in, const int* in_sizes, int n_in,
                              void* d_out, int out_size, void* d_ws, size_t ws_size,
                              hipStream_t stream) {
    const float* x       = (const float*)d_in[0];
    const int*   ei      = (const int*)d_in[1];
    const float* deg_inv = (const float*)d_in[2];
    const float* W       = (const float*)d_in[3];
    const float* bias    = (const float*)d_in[4];
    float*       out     = (float*)d_out;

    const int* src = ei;
    const int* dst = ei + N_EDGES;

    // ws layout: mb (bf16 m) | counts | incl | cursor | bsum | boff | csr | Wb
    unsigned short* mb = (unsigned short*)d_ws;
    size_t mb_bytes = (size_t)N_NODES * DIM_IN * sizeof(unsigned short);   // 25.6 MB
    int* counts = (int*)((char*)d_ws + mb_bytes);
    int* incl   = counts + N_NODES;
    int* cursor = incl + N_NODES;
    int* bsum   = cursor + N_NODES;
    int* boff   = bsum + 128;
    int* csr    = boff + 128;
    unsigned short* Wb = (unsigned short*)(csr + N_EDGES);

    hipMemsetAsync(counts, 0, N_NODES * sizeof(int), stream);
    k_cvtW<<<(DIM_IN * DIM_OUT) / 256, 256, 0, stream>>>(W, Wb);
    k_count<<<N_EDGES / 256, 256, 0, stream>>>(dst, counts);
    k_scan1<<<SCAN_NB, SCAN_B, 0, stream>>>(counts, incl, bsum);
    k_scan2<<<1, 128, 0, stream>>>(bsum, boff);
    k_scan3<<<SCAN_NB, SCAN_B, 0, stream>>>(counts, incl, boff, cursor);
    k_fill<<<N_EDGES / 256, 256, 0, stream>>>(src, dst, cursor, csr);
    k_agg<<<(N_NODES + 3) / 4, 256, 0, stream>>>(x, csr, incl, counts, deg_inv, mb);

    k_mfma_gemm<<<(N_NODES + 63) / 64, 256, 0, stream>>>(mb, Wb, bias, out);
}

// Round 4
// 198.567 us; speedup vs baseline: 10.2046x; 1.2226x over previous
//
#include <hip/hip_runtime.h>
#include <math.h>

#define N_NODES 100000
#define N_EDGES 800000
#define DIM_IN 128
#define DIM_OUT 256
#define NPB 128   // nodes per block in the MFMA GEMM (2 sub-tiles of 64)

constexpr int SCAN_B  = 1024;
constexpr int SCAN_NB = (N_NODES + SCAN_B - 1) / SCAN_B;   // 98

typedef __bf16 bf16x8 __attribute__((ext_vector_type(8)));
typedef float  f32x4  __attribute__((ext_vector_type(4)));

// ---------------- CSR build ------------------------------------------------
__global__ __launch_bounds__(256) void k_count(const int* __restrict__ dst,
                                               int* __restrict__ counts) {
    int e = blockIdx.x * 256 + threadIdx.x;   // grid exact: 800000/256
    atomicAdd(&counts[dst[e]], 1);
}

__global__ __launch_bounds__(SCAN_B) void k_scan1(const int* __restrict__ counts,
                                                  int* __restrict__ incl,
                                                  int* __restrict__ bsum) {
    __shared__ int s[SCAN_B];
    int tid = threadIdx.x;
    int i = blockIdx.x * SCAN_B + tid;
    int v = (i < N_NODES) ? counts[i] : 0;
    s[tid] = v;
    __syncthreads();
    for (int off = 1; off < SCAN_B; off <<= 1) {
        int t = (tid >= off) ? s[tid - off] : 0;
        __syncthreads();
        s[tid] += t;
        __syncthreads();
    }
    if (i < N_NODES) incl[i] = s[tid];
    if (tid == SCAN_B - 1) bsum[blockIdx.x] = s[tid];
}

__global__ __launch_bounds__(128) void k_scan2(const int* __restrict__ bsum,
                                               int* __restrict__ boff) {
    __shared__ int s[128];
    int tid = threadIdx.x;
    int v = (tid < SCAN_NB) ? bsum[tid] : 0;
    s[tid] = v;
    __syncthreads();
    for (int off = 1; off < 128; off <<= 1) {
        int t = (tid >= off) ? s[tid - off] : 0;
        __syncthreads();
        s[tid] += t;
        __syncthreads();
    }
    if (tid < SCAN_NB) boff[tid] = s[tid];
}

__global__ __launch_bounds__(SCAN_B) void k_scan3(const int* __restrict__ counts,
                                                  int* __restrict__ incl,
                                                  const int* __restrict__ boff,
                                                  int* __restrict__ cursor) {
    int i = blockIdx.x * SCAN_B + threadIdx.x;
    if (i < N_NODES) {
        int base = (blockIdx.x > 0) ? boff[blockIdx.x - 1] : 0;
        int v = incl[i] + base;
        incl[i] = v;                 // global inclusive scan
        cursor[i] = v - counts[i];   // row start (exclusive)
    }
}

__global__ __launch_bounds__(256) void k_fill(const int* __restrict__ src,
                                              const int* __restrict__ dst,
                                              int* __restrict__ cursor,
                                              int* __restrict__ csr) {
    int e = blockIdx.x * 256 + threadIdx.x;
    int pos = atomicAdd(&cursor[dst[e]], 1);
    csr[pos] = src[e];
}

// ---------------- dtype conversions ----------------------------------------
__global__ __launch_bounds__(256) void k_cvtW(const float* __restrict__ W,
                                              unsigned short* __restrict__ Wb) {
    int i = blockIdx.x * 256 + threadIdx.x;   // 32768 total, grid exact
    Wb[i] = __builtin_bit_cast(unsigned short, (__bf16)W[i]);
}

__global__ __launch_bounds__(256) void k_cvtX(const float* __restrict__ x,
                                              unsigned short* __restrict__ xb) {
    int i = blockIdx.x * 256 + threadIdx.x;   // float4 index; grid exact 12500
    const float4 v = reinterpret_cast<const float4*>(x)[i];
    unsigned short s0 = __builtin_bit_cast(unsigned short, (__bf16)v.x);
    unsigned short s1 = __builtin_bit_cast(unsigned short, (__bf16)v.y);
    unsigned short s2 = __builtin_bit_cast(unsigned short, (__bf16)v.z);
    unsigned short s3 = __builtin_bit_cast(unsigned short, (__bf16)v.w);
    uint2 o;
    o.x = (unsigned)s0 | ((unsigned)s1 << 16);
    o.y = (unsigned)s2 | ((unsigned)s3 << 16);
    reinterpret_cast<uint2*>(xb)[i] = o;
}

// ---------------- Aggregate (bf16 x): mb[n] = bf16(deg_inv[n]*sum xb[src]) -
__device__ __forceinline__ float bflo(unsigned u) {
    return __builtin_bit_cast(float, u << 16);
}
__device__ __forceinline__ float bfhi(unsigned u) {
    return __builtin_bit_cast(float, u & 0xffff0000u);
}

__global__ __launch_bounds__(256) void k_agg_b(const unsigned short* __restrict__ xb,
                                               const int* __restrict__ csr,
                                               const int* __restrict__ incl,
                                               const int* __restrict__ counts,
                                               const float* __restrict__ deg_inv,
                                               unsigned short* __restrict__ mb) {
    int wave = threadIdx.x >> 6;
    int lane = threadIdx.x & 63;
    int node = blockIdx.x * 4 + wave;        // grid exact: 25000*4
    int end = __builtin_amdgcn_readfirstlane(incl[node]);
    int beg = end - __builtin_amdgcn_readfirstlane(counts[node]);
    float a0 = 0.f, a1 = 0.f;
    int e = beg;
    for (; e + 1 < end; e += 2) {
        int s0 = csr[e];
        int s1 = csr[e + 1];
        unsigned u0 = reinterpret_cast<const unsigned*>(xb + (size_t)s0 * DIM_IN)[lane];
        unsigned u1 = reinterpret_cast<const unsigned*>(xb + (size_t)s1 * DIM_IN)[lane];
        a0 += bflo(u0) + bflo(u1);
        a1 += bfhi(u0) + bfhi(u1);
    }
    if (e < end) {
        int s0 = csr[e];
        unsigned u0 = reinterpret_cast<const unsigned*>(xb + (size_t)s0 * DIM_IN)[lane];
        a0 += bflo(u0);
        a1 += bfhi(u0);
    }
    float d = deg_inv[node];
    unsigned short q0 = __builtin_bit_cast(unsigned short, (__bf16)(a0 * d));
    unsigned short q1 = __builtin_bit_cast(unsigned short, (__bf16)(a1 * d));
    reinterpret_cast<unsigned*>(mb + (size_t)node * DIM_IN)[lane] =
        (unsigned)q0 | ((unsigned)q1 << 16);
}

// f32-x fallback (if ws too small for xb)
__global__ __launch_bounds__(256) void k_agg_f(const float* __restrict__ x,
                                               const int* __restrict__ csr,
                                               const int* __restrict__ incl,
                                               const int* __restrict__ counts,
                                               const float* __restrict__ deg_inv,
                                               unsigned short* __restrict__ mb) {
    int wave = threadIdx.x >> 6;
    int lane = threadIdx.x & 63;
    int node = blockIdx.x * 4 + wave;
    int end = __builtin_amdgcn_readfirstlane(incl[node]);
    int beg = end - __builtin_amdgcn_readfirstlane(counts[node]);
    float a0 = 0.f, a1 = 0.f;
    for (int e = beg; e < end; ++e) {
        int s = csr[e];
        const float2 v = *reinterpret_cast<const float2*>(x + (size_t)s * DIM_IN + lane * 2);
        a0 += v.x;
        a1 += v.y;
    }
    float d = deg_inv[node];
    unsigned short q0 = __builtin_bit_cast(unsigned short, (__bf16)(a0 * d));
    unsigned short q1 = __builtin_bit_cast(unsigned short, (__bf16)(a1 * d));
    reinterpret_cast<unsigned*>(mb + (size_t)node * DIM_IN)[lane] =
        (unsigned)q0 | ((unsigned)q1 << 16);
}

// ---------------- GELU (tanh form, branch-free) ----------------------------
// max |gelu_tanh - gelu_erf| ~ 1e-3, far under the bf16 validation threshold.
__device__ __forceinline__ float gelu_f(float h) {
    float u = h * h;
    float inner = h * (0.7978845608f + 0.0356774081f * u);  // 0.79788456*(1+0.044715 h^2)
    float a = __builtin_amdgcn_exp2f(-2.8853900818f * __builtin_fabsf(inner)); // exp(-2|y|)
    float t = (1.f - a) * __builtin_amdgcn_rcpf(1.f + a);   // tanh(|y|)
    t = __builtin_copysignf(t, inner);
    return 0.5f * h * (1.f + t);
}

// ---------------- MFMA GEMM + bias + GELU ----------------------------------
// Block: 256 thr = 4 waves; wave w owns out cols [w*64, w*64+64) for NPB
// nodes. B (W) fragments preloaded to registers ONCE (64 VGPR), reused for
// both 64-node sub-tiles. All 16 A loads batched before the MFMA block.
__global__ __launch_bounds__(256) void k_mfma_gemm(
    const unsigned short* __restrict__ mb,
    const unsigned short* __restrict__ Wb,
    const float* __restrict__ bias,
    float* __restrict__ out)
{
    const int wave = threadIdx.x >> 6;
    const int lane = threadIdx.x & 63;
    const int lr = lane & 15;     // A-row / B-col / D-col
    const int kg = lane >> 4;     // k-group (8 contiguous k)
    const int n_base = blockIdx.x * NPB;
    const int o0 = wave * 64;

    bf16x8 bfr[4][4];
#pragma unroll
    for (int nt = 0; nt < 4; ++nt)
#pragma unroll
        for (int ks = 0; ks < 4; ++ks)
            bfr[nt][ks] = *reinterpret_cast<const bf16x8*>(
                Wb + (size_t)(o0 + nt * 16 + lr) * DIM_IN + ks * 32 + kg * 8);

    float bval[4];
#pragma unroll
    for (int nt = 0; nt < 4; ++nt) bval[nt] = bias[o0 + nt * 16 + lr];

#pragma unroll
    for (int st = 0; st < NPB / 64; ++st) {
        const int n0 = n_base + st * 64;

        bf16x8 afr[4][4];
#pragma unroll
        for (int mt = 0; mt < 4; ++mt) {
            int node = n0 + mt * 16 + lr;
            node = node < N_NODES ? node : N_NODES - 1;
            const unsigned short* arow = mb + (size_t)node * DIM_IN;
#pragma unroll
            for (int ks = 0; ks < 4; ++ks)
                afr[mt][ks] = *reinterpret_cast<const bf16x8*>(arow + ks * 32 + kg * 8);
        }

        f32x4 acc[4][4] = {};
#pragma unroll
        for (int ks = 0; ks < 4; ++ks)
#pragma unroll
            for (int mt = 0; mt < 4; ++mt)
#pragma unroll
                for (int nt = 0; nt < 4; ++nt)
                    acc[mt][nt] = __builtin_amdgcn_mfma_f32_16x16x32_bf16(
                        afr[mt][ks], bfr[nt][ks], acc[mt][nt], 0, 0, 0);

        // D mapping: col = lane&15, row = (lane>>4)*4 + reg.
        const int rb = kg * 4;
#pragma unroll
        for (int mt = 0; mt < 4; ++mt) {
#pragma unroll
            for (int r = 0; r < 4; ++r) {
                int node = n0 + mt * 16 + rb + r;
                if (node < N_NODES) {
                    float* orow = out + (size_t)node * DIM_OUT + o0;
#pragma unroll
                    for (int nt = 0; nt < 4; ++nt) {
                        float h = acc[mt][nt][r] + bval[nt];
                        orow[nt * 16 + lr] = gelu_f(h);
                    }
                }
            }
        }
    }
}

extern "C" void kernel_launch(void* const* d_in, const int* in_sizes, int n_in,
                              void* d_out, int out_size, void* d_ws, size_t ws_size,
                              hipStream_t stream) {
    const float* x       = (const float*)d_in[0];
    const int*   ei      = (const int*)d_in[1];
    const float* deg_inv = (const float*)d_in[2];
    const float* W       = (const float*)d_in[3];
    const float* bias    = (const float*)d_in[4];
    float*       out     = (float*)d_out;

    const int* src = ei;
    const int* dst = ei + N_EDGES;

    // ws layout: mb | counts | incl | cursor | bsum | boff | csr | Wb | xb
    unsigned short* mb = (unsigned short*)d_ws;
    size_t mb_bytes = (size_t)N_NODES * DIM_IN * sizeof(unsigned short);   // 25.6 MB
    int* counts = (int*)((char*)d_ws + mb_bytes);
    int* incl   = counts + N_NODES;
    int* cursor = incl + N_NODES;
    int* bsum   = cursor + N_NODES;
    int* boff   = bsum + 128;
    int* csr    = boff + 128;
    unsigned short* Wb = (unsigned short*)(csr + N_EDGES);
    unsigned short* xb = Wb + DIM_IN * DIM_OUT;
    size_t need_xb = mb_bytes + sizeof(int) * ((size_t)3 * N_NODES + 256 + N_EDGES)
                   + sizeof(unsigned short) * ((size_t)DIM_IN * DIM_OUT
                                               + (size_t)N_NODES * DIM_IN);

    hipMemsetAsync(counts, 0, N_NODES * sizeof(int), stream);
    k_cvtW<<<(DIM_IN * DIM_OUT) / 256, 256, 0, stream>>>(W, Wb);
    k_count<<<N_EDGES / 256, 256, 0, stream>>>(dst, counts);
    k_scan1<<<SCAN_NB, SCAN_B, 0, stream>>>(counts, incl, bsum);
    k_scan2<<<1, 128, 0, stream>>>(bsum, boff);
    k_scan3<<<SCAN_NB, SCAN_B, 0, stream>>>(counts, incl, boff, cursor);
    k_fill<<<N_EDGES / 256, 256, 0, stream>>>(src, dst, cursor, csr);

    if (ws_size >= need_xb) {
        k_cvtX<<<(N_NODES * DIM_IN / 4) / 256, 256, 0, stream>>>(x, xb);
        k_agg_b<<<N_NODES / 4, 256, 0, stream>>>(xb, csr, incl, counts, deg_inv, mb);
    } else {
        k_agg_f<<<N_NODES / 4, 256, 0, stream>>>(x, csr, incl, counts, deg_inv, mb);
    }

    k_mfma_gemm<<<(N_NODES + NPB - 1) / NPB, 256, 0, stream>>>(mb, Wb, bias, out);
}